// Round 2
// baseline (1079.518 us; speedup 1.0000x reference)
//
#include <hip/hip_runtime.h>

typedef __attribute__((ext_vector_type(8))) short bf16x8;
typedef __attribute__((ext_vector_type(4))) float f32x4;

#define NBATCH 4
#define LSEQ   4096
#define DMODEL 1024
#define DI     2048
#define DST    16
#define NCHUNK 64
#define CLEN   (LSEQ/NCHUNK)   // 64

// ---------------- helpers ----------------
__device__ __forceinline__ ushort f2bf(float x){
  union { float f; unsigned u; } v; v.f = x;
  unsigned r = v.u + 0x7FFFu + ((v.u >> 16) & 1u);
  return (ushort)(r >> 16);
}
__device__ __forceinline__ float bf2f(ushort h){
  union { unsigned u; float f; } v; v.u = ((unsigned)h) << 16;
  return v.f;
}
__device__ __forceinline__ float fexp2(float x){
  float r; asm("v_exp_f32 %0, %1" : "=v"(r) : "v"(x)); return r;
}
__device__ __forceinline__ float fsilu(float x){
  return x * __builtin_amdgcn_rcpf(1.f + __expf(-x));
}
__device__ __forceinline__ void gld_lds16(const ushort* g, ushort* l){
  __builtin_amdgcn_global_load_lds(
    (const __attribute__((address_space(1))) unsigned int*)g,
    (__attribute__((address_space(3))) unsigned int*)l, 16, 0, 0);
}

// ---------------- elementwise cast f32 -> bf16 (x4 vectorized) ----------------
__global__ void cast_f32_bf16(const float* __restrict__ in, ushort* __restrict__ out, int n4){
  int i = blockIdx.x*blockDim.x + threadIdx.x;
  if (i >= n4) return;
  float4 v = ((const float4*)in)[i];
  ushort4 o; o.x=f2bf(v.x); o.y=f2bf(v.y); o.z=f2bf(v.z); o.w=f2bf(v.w);
  ((ushort4*)out)[i] = o;
}

// ---------------- transpose + cast: out[c][r] = bf16(in[r][c]) ----------------
__global__ void transpose_cast(const float* __restrict__ in, ushort* __restrict__ out, int R, int C){
  __shared__ float tile[32][33];
  int c0 = blockIdx.x*32, r0 = blockIdx.y*32;
  int tx = threadIdx.x, ty = threadIdx.y;   // 32 x 8
  #pragma unroll
  for (int i=0;i<4;i++){
    int r = r0 + ty + i*8;
    if (r < R && (c0+tx) < C) tile[ty+i*8][tx] = in[(size_t)r*C + c0 + tx];
  }
  __syncthreads();
  #pragma unroll
  for (int i=0;i<4;i++){
    int c = c0 + ty + i*8;
    if (c < C && (r0+tx) < R) out[(size_t)c*R + r0 + tx] = f2bf(tile[tx][ty+i*8]);
  }
}

// A2n = -exp(A_log) * log2(e)
__global__ void prep_a2(const float* __restrict__ A_log, float* __restrict__ A2n, int n){
  int i = blockIdx.x*blockDim.x + threadIdx.x;
  if (i < n) A2n[i] = -expf(A_log[i]) * 1.4426950408889634f;
}

// ---------------- bf16 MFMA GEMM, B in N x K (transposed) layout ----------------
// 128x128 tile, BK=32, 256 threads (4 waves 2x2), 16x16x32 MFMA, 4x4 frags/wave.
// MODE 0: N=4096: col<2048 -> out0 bf16 raw (xs), col>=2048 -> out1 bf16 silu (sz)
// MODE 1: N=2048: out0 bf16 = softplus(v + bias[col])         (dt)
// MODE 2: N=1024: out0 f32 = v                                 (final out)
// MODE 3: N=128:  out0 f32 [rr*16+col] = v for col<16          (Bs)
template<int MODE>
__global__ __launch_bounds__(256, 2)
void gemm_bt(const ushort* __restrict__ A, const ushort* __restrict__ Bm, const int K,
             void* __restrict__ out0, void* __restrict__ out1, const float* __restrict__ bias)
{
  __shared__ __align__(16) ushort As[128*32];
  __shared__ __align__(16) ushort Bs[128*32];
  const int tid = threadIdx.x;
  const int wave = tid >> 6, lane = tid & 63;
  const int bm = blockIdx.y, bn = blockIdx.x;
  const int wm = wave >> 1, wn = wave & 1;
  const int lm = lane & 15, kk = (lane >> 4) * 8;
  f32x4 acc[4][4];
  #pragma unroll
  for (int i=0;i<4;i++)
    #pragma unroll
    for (int j=0;j<4;j++) acc[i][j] = (f32x4){0.f,0.f,0.f,0.f};

  const size_t Abase = (size_t)bm*128*K;
  const size_t Bbase = (size_t)bn*128*K;
  for (int k0 = 0; k0 < K; k0 += 32) {
    __syncthreads();
    #pragma unroll
    for (int j=0;j<2;j++){
      int f = j*2048 + tid*8;       // flat bf16 elem within the 128x32 tile
      gld_lds16(A  + Abase + (size_t)(f>>5)*K + k0 + (f&31), &As[j*2048 + wave*512]);
      gld_lds16(Bm + Bbase + (size_t)(f>>5)*K + k0 + (f&31), &Bs[j*2048 + wave*512]);
    }
    __syncthreads();
    bf16x8 af[4], bfv[4];
    #pragma unroll
    for (int mi=0;mi<4;mi++) af[mi]  = *(const bf16x8*)&As[(wm*64+mi*16+lm)*32 + kk];
    #pragma unroll
    for (int ni=0;ni<4;ni++) bfv[ni] = *(const bf16x8*)&Bs[(wn*64+ni*16+lm)*32 + kk];
    #pragma unroll
    for (int mi=0;mi<4;mi++)
      #pragma unroll
      for (int ni=0;ni<4;ni++)
        acc[mi][ni] = __builtin_amdgcn_mfma_f32_16x16x32_bf16(af[mi], bfv[ni], acc[mi][ni], 0, 0, 0);
  }
  const int row0 = bm*128 + wm*64;
  const int col0 = bn*128 + wn*64;
  #pragma unroll
  for (int mi=0;mi<4;mi++){
    #pragma unroll
    for (int ni=0;ni<4;ni++){
      int c = col0 + ni*16 + lm;
      int rbase = row0 + mi*16 + (lane>>4)*4;
      #pragma unroll
      for (int j=0;j<4;j++){
        float v = acc[mi][ni][j];
        size_t rr = (size_t)(rbase + j);
        if (MODE==0){
          if (c < 2048) ((ushort*)out0)[rr*2048 + c] = f2bf(v);
          else          ((ushort*)out1)[rr*2048 + (c-2048)] = f2bf(fsilu(v));
        } else if (MODE==1){
          float u = v + bias[c];
          float sp = (u > 15.f) ? u : logf(1.f + __expf(u));
          ((ushort*)out0)[rr*2048 + c] = f2bf(sp);
        } else if (MODE==2){
          ((float*)out0)[rr*1024 + c] = v;
        } else {
          if (c < 16) ((float*)out0)[rr*16 + c] = v;
        }
      }
    }
  }
}

// ---------------- depthwise causal conv K=4 + silu, bf16 in/out (one batch) ----------------
__global__ __launch_bounds__(256)
void conv_silu(const ushort* __restrict__ xs_raw, const float* __restrict__ w,
               const float* __restrict__ cb, ushort* __restrict__ out)
{
  int idx = blockIdx.x*256 + threadIdx.x;   // (LSEQ/8)*DI threads
  int c  = idx & (DI-1);
  int l8 = idx >> 11;                       // 0..511
  int l0 = l8*8;
  float w0=w[c*4+0], w1=w[c*4+1], w2=w[c*4+2], w3=w[c*4+3];
  float bias = cb[c];
  const ushort* base = xs_raw + c;
  float v[11];
  #pragma unroll
  for (int i=0;i<11;i++){
    int t = l0 - 3 + i;
    v[i] = (t >= 0) ? bf2f(base[(size_t)t*DI]) : 0.f;
  }
  ushort* ob = out + (size_t)l0*DI + c;
  #pragma unroll
  for (int i=0;i<8;i++){
    float acc = bias + v[i]*w0 + v[i+1]*w1 + v[i+2]*w2 + v[i+3]*w3;
    ob[(size_t)i*DI] = f2bf(fsilu(acc));
  }
}

// ---------------- scan phase 1: per-chunk local scan, h0=0 (one batch) ----------------
__global__ __launch_bounds__(256)
void scan_phase1(const ushort* __restrict__ dtb, const float* __restrict__ bsb,
                 const float* __restrict__ A2n, float* __restrict__ hlocal,
                 float* __restrict__ sumdt)
{
  __shared__ __align__(16) float bs_s[CLEN][DST];
  const int c  = blockIdx.x*256 + threadIdx.x;
  const int ch = blockIdx.y;
  ((float4*)bs_s)[threadIdx.x] = ((const float4*)(bsb + (size_t)ch*CLEN*DST))[threadIdx.x];
  __syncthreads();
  float a2[DST];
  #pragma unroll
  for (int i=0;i<4;i++) *(float4*)&a2[i*4] = *(const float4*)&A2n[(size_t)c*DST + i*4];
  float h[DST];
  #pragma unroll
  for (int s=0;s<DST;s++) h[s] = 0.f;
  float sdt = 0.f;
  const ushort* dtp = dtb + (size_t)ch*CLEN*DI + c;
  for (int t=0;t<CLEN;t++){
    float d = bf2f(dtp[(size_t)t*DI]);
    sdt += d;
    float bsv[DST];
    #pragma unroll
    for (int i=0;i<4;i++) *(float4*)&bsv[i*4] = *(const float4*)&bs_s[t][i*4];
    #pragma unroll
    for (int s=0;s<DST;s++) h[s] = fmaf(h[s], fexp2(a2[s]*d), bsv[s]);
  }
  size_t o = ((size_t)ch*DI + c)*DST;
  #pragma unroll
  for (int i=0;i<4;i++) *(float4*)&hlocal[o + i*4] = *(float4*)&h[i*4];
  sumdt[(size_t)ch*DI + c] = sdt;
}

// ---------------- scan phase 2: chunk-level prefix over 64 chunks (one batch) ----------------
__global__ void scan_phase2(const float* __restrict__ hlocal, const float* __restrict__ sumdt,
                            const float* __restrict__ A2n, float* __restrict__ hstart)
{
  int id = blockIdx.x*blockDim.x + threadIdx.x;   // DI*DST = 32768
  int s = id & (DST-1);
  int c = id >> 4;
  float a2 = A2n[(size_t)c*DST + s];
  float h = 0.f;
  for (int ch=0; ch<NCHUNK; ++ch){
    size_t o = ((size_t)ch*DI + c)*DST + s;
    hstart[o] = h;
    float sd = sumdt[(size_t)ch*DI + c];
    h = fmaf(h, fexp2(a2*sd), hlocal[o]);
  }
}

// ---------------- scan phase 3: replay with carry, emit y*silu(z) bf16 (one batch) ----------------
__global__ __launch_bounds__(256)
void scan_phase3(const ushort* __restrict__ dtb, const float* __restrict__ bsb,
                 const float* __restrict__ A2n, const float* __restrict__ hstart,
                 const ushort* __restrict__ xsbf, const ushort* __restrict__ szb,
                 const float* __restrict__ Dv, ushort* __restrict__ ybf)
{
  __shared__ __align__(16) float bs_s[CLEN][DST];
  const int c  = blockIdx.x*256 + threadIdx.x;
  const int ch = blockIdx.y;
  ((float4*)bs_s)[threadIdx.x] = ((const float4*)(bsb + (size_t)ch*CLEN*DST))[threadIdx.x];
  __syncthreads();
  float a2[DST];
  #pragma unroll
  for (int i=0;i<4;i++) *(float4*)&a2[i*4] = *(const float4*)&A2n[(size_t)c*DST + i*4];
  float h[DST];
  size_t ho = ((size_t)ch*DI + c)*DST;
  #pragma unroll
  for (int i=0;i<4;i++) *(float4*)&h[i*4] = *(const float4*)&hstart[ho + i*4];
  const float Dc = Dv[c];
  const size_t base = (size_t)ch*CLEN*DI + c;
  const ushort* dtp = dtb + base;
  const ushort* xp  = xsbf + base;
  const ushort* szp = szb + base;
  ushort* yp = ybf + base;
  for (int t=0;t<CLEN;t++){
    float d = bf2f(dtp[(size_t)t*DI]);
    float bsv[DST];
    #pragma unroll
    for (int i=0;i<4;i++) *(float4*)&bsv[i*4] = *(const float4*)&bs_s[t][i*4];
    #pragma unroll
    for (int s=0;s<DST;s++) h[s] = fmaf(h[s], fexp2(a2[s]*d), bsv[s]);
    float s0 = (h[0]+h[1]) + (h[2]+h[3]);
    float s1 = (h[4]+h[5]) + (h[6]+h[7]);
    float s2 = (h[8]+h[9]) + (h[10]+h[11]);
    float s3 = (h[12]+h[13]) + (h[14]+h[15]);
    float ysum = (s0+s1) + (s2+s3);
    float xv = bf2f(xp[(size_t)t*DI]);
    float yv = fmaf(Dc, xv, ysum);
    yp[(size_t)t*DI] = f2bf(yv * bf2f(szp[(size_t)t*DI]));
  }
}

// ---------------- launch ----------------
extern "C" void kernel_launch(void* const* d_in, const int* in_sizes, int n_in,
                              void* d_out, int out_size, void* d_ws, size_t ws_size,
                              hipStream_t stream)
{
  if (n_in < 10) return;
  const float* x     = (const float*)d_in[0];
  const float* W_in  = (const float*)d_in[1];
  const float* convw = (const float*)d_in[2];
  const float* convb = (const float*)d_in[3];
  const float* A_log = (const float*)d_in[4];
  const float* Dvec  = (const float*)d_in[5];
  const float* W_x   = (const float*)d_in[6];
  const float* W_dt  = (const float*)d_in[7];
  const float* b_dt  = (const float*)d_in[8];
  const float* W_out = (const float*)d_in[9];
  float* out = (float*)d_out;

  char* p = (char*)d_ws;
  auto alloc = [&](size_t n){ char* r = p; p += (n + 255) & ~(size_t)255; return r; };
  // weights (once)
  ushort* WinT   = (ushort*)alloc((size_t)(2*DI)*DMODEL*2);   //  8.4 MB
  ushort* WdtT   = (ushort*)alloc((size_t)DI*DI*2);           //  8.4 MB
  ushort* WoutT  = (ushort*)alloc((size_t)DMODEL*DI*2);       //  4.2 MB
  ushort* WxT    = (ushort*)alloc((size_t)128*DI*2);          //  0.5 MB
  float*  A2n    = (float*)alloc((size_t)DI*DST*4);           //  0.1 MB
  // per-batch activations (reused across the 4 batches)
  ushort* xbf    = (ushort*)alloc((size_t)LSEQ*DMODEL*2);     //  8.4 MB
  ushort* xsr    = (ushort*)alloc((size_t)LSEQ*DI*2);         // 16.8 MB raw xs
  ushort* szb    = (ushort*)alloc((size_t)LSEQ*DI*2);         // 16.8 MB silu(z)
  ushort* xsb    = (ushort*)alloc((size_t)LSEQ*DI*2);         // 16.8 MB conv+silu
  ushort* dtb    = (ushort*)alloc((size_t)LSEQ*DI*2);         // 16.8 MB dt
  ushort* ybf    = (ushort*)alloc((size_t)LSEQ*DI*2);         // 16.8 MB y
  float*  BsB    = (float*)alloc((size_t)LSEQ*DST*4);         //  0.3 MB
  float*  hlocal = (float*)alloc((size_t)NCHUNK*DI*DST*4);    //  8.4 MB
  float*  hstart = (float*)alloc((size_t)NCHUNK*DI*DST*4);    //  8.4 MB
  float*  sumdt  = (float*)alloc((size_t)NCHUNK*DI*4);        //  0.5 MB
  if ((size_t)(p - (char*)d_ws) > ws_size) return;   // ws too small: no OOB

  // weight prep
  transpose_cast<<<dim3((2*DI)/32, DMODEL/32), dim3(32,8), 0, stream>>>(W_in, WinT, DMODEL, 2*DI);
  transpose_cast<<<dim3(DI/32, DI/32), dim3(32,8), 0, stream>>>(W_dt, WdtT, DI, DI);
  transpose_cast<<<dim3(DMODEL/32, DI/32), dim3(32,8), 0, stream>>>(W_out, WoutT, DI, DMODEL);
  hipMemsetAsync(WxT, 0, (size_t)128*DI*2, stream);
  transpose_cast<<<dim3(1, DI/32), dim3(32,8), 0, stream>>>(W_x, WxT, DI, DST);
  prep_a2<<<(DI*DST + 255)/256, 256, 0, stream>>>(A_log, A2n, DI*DST);

  for (int b = 0; b < NBATCH; ++b) {
    const float* xb = x + (size_t)b*LSEQ*DMODEL;
    float* outb = out + (size_t)b*LSEQ*DMODEL;
    // cast x -> bf16
    cast_f32_bf16<<<(LSEQ*DMODEL/4 + 255)/256, 256, 0, stream>>>(xb, xbf, LSEQ*DMODEL/4);
    // xz = x @ W_in ; xs raw bf16 + silu(z) bf16
    gemm_bt<0><<<dim3((2*DI)/128, LSEQ/128), 256, 0, stream>>>(xbf, WinT, DMODEL, xsr, szb, nullptr);
    // depthwise conv + silu -> bf16
    conv_silu<<<(LSEQ/8)*DI/256, 256, 0, stream>>>(xsr, convw, convb, xsb);
    // dt = softplus(xs @ W_dt + b_dt) -> bf16
    gemm_bt<1><<<dim3(DI/128, LSEQ/128), 256, 0, stream>>>(xsb, WdtT, DI, dtb, nullptr, b_dt);
    // Bs = xs @ W_x (N padded to 128) -> f32
    gemm_bt<3><<<dim3(1, LSEQ/128), 256, 0, stream>>>(xsb, WxT, DI, BsB, nullptr, nullptr);
    // chunked scan
    scan_phase1<<<dim3(DI/256, NCHUNK), 256, 0, stream>>>(dtb, BsB, A2n, hlocal, sumdt);
    scan_phase2<<<(DI*DST)/256, 256, 0, stream>>>(hlocal, sumdt, A2n, hstart);
    scan_phase3<<<dim3(DI/256, NCHUNK), 256, 0, stream>>>(dtb, BsB, A2n, hstart, xsb, szb, Dvec, ybf);
    // out = y @ W_out (f32)
    gemm_bt<2><<<dim3(DMODEL/128, LSEQ/128), 256, 0, stream>>>(ybf, WoutT, DI, outb, nullptr, nullptr);
  }
}

// Round 3
// 960.698 us; speedup vs baseline: 1.1237x; 1.1237x over previous
//
#include <hip/hip_runtime.h>

typedef __attribute__((ext_vector_type(8))) short bf16x8;
typedef __attribute__((ext_vector_type(4))) float f32x4;

#define NBATCH 4
#define LSEQ   4096
#define DMODEL 1024
#define DI     2048
#define DST    16
#define NCHUNK 64
#define CLEN   (LSEQ/NCHUNK)   // 64
#define KSPLIT 8               // split-K factor for Bs GEMM

// ---------------- helpers ----------------
__device__ __forceinline__ ushort f2bf(float x){
  union { float f; unsigned u; } v; v.f = x;
  unsigned r = v.u + 0x7FFFu + ((v.u >> 16) & 1u);
  return (ushort)(r >> 16);
}
__device__ __forceinline__ float bf2f(ushort h){
  union { unsigned u; float f; } v; v.u = ((unsigned)h) << 16;
  return v.f;
}
__device__ __forceinline__ float fexp2(float x){
  float r; asm("v_exp_f32 %0, %1" : "=v"(r) : "v"(x)); return r;
}
__device__ __forceinline__ float fsilu(float x){
  return x * __builtin_amdgcn_rcpf(1.f + __expf(-x));
}
__device__ __forceinline__ void gld_lds16(const ushort* g, ushort* l){
  __builtin_amdgcn_global_load_lds(
    (const __attribute__((address_space(1))) unsigned int*)g,
    (__attribute__((address_space(3))) unsigned int*)l, 16, 0, 0);
}

// ---------------- elementwise cast f32 -> bf16 (x4 vectorized) ----------------
__global__ void cast_f32_bf16(const float* __restrict__ in, ushort* __restrict__ out, int n4){
  int i = blockIdx.x*blockDim.x + threadIdx.x;
  if (i >= n4) return;
  float4 v = ((const float4*)in)[i];
  ushort4 o; o.x=f2bf(v.x); o.y=f2bf(v.y); o.z=f2bf(v.z); o.w=f2bf(v.w);
  ((ushort4*)out)[i] = o;
}

// ---------------- transpose + cast: out[c][r] = bf16(in[r][c]) ----------------
__global__ void transpose_cast(const float* __restrict__ in, ushort* __restrict__ out, int R, int C){
  __shared__ float tile[32][33];
  int c0 = blockIdx.x*32, r0 = blockIdx.y*32;
  int tx = threadIdx.x, ty = threadIdx.y;   // 32 x 8
  #pragma unroll
  for (int i=0;i<4;i++){
    int r = r0 + ty + i*8;
    if (r < R && (c0+tx) < C) tile[ty+i*8][tx] = in[(size_t)r*C + c0 + tx];
  }
  __syncthreads();
  #pragma unroll
  for (int i=0;i<4;i++){
    int c = c0 + ty + i*8;
    if (c < C && (r0+tx) < R) out[(size_t)c*R + r0 + tx] = f2bf(tile[tx][ty+i*8]);
  }
}

// A2n = -exp(A_log) * log2(e)
__global__ void prep_a2(const float* __restrict__ A_log, float* __restrict__ A2n, int n){
  int i = blockIdx.x*blockDim.x + threadIdx.x;
  if (i < n) A2n[i] = -expf(A_log[i]) * 1.4426950408889634f;
}

// Check whether a2[c][s] == (s+1)*a2[c][0] for all channels (enables 1-exp scan path).
__global__ void check_a2(const float* __restrict__ A2n, int* __restrict__ flag){
  int c = blockIdx.x*blockDim.x + threadIdx.x;
  if (c >= DI) return;
  const float* a = A2n + (size_t)c*DST;
  float a0 = a[0];
  int bad = 0;
  #pragma unroll
  for (int s=1;s<DST;s++){
    float want = (float)(s+1)*a0;
    if (fabsf(a[s] - want) > 1e-4f*fabsf(want) + 1e-12f) bad = 1;
  }
  if (bad) atomicOr(flag, 1);
}

// ---------------- bf16 MFMA GEMM, B in N x K (transposed) layout ----------------
// 128x128 tile, BK=32, 256 threads (4 waves 2x2), 16x16x32 MFMA, 4x4 frags/wave.
// MODE 0: N=4096: col<2048 -> out0 bf16 raw (xs), col>=2048 -> out1 bf16 silu (sz)
// MODE 1: N=2048: out0 bf16 = softplus(v + bias[col])         (dt)
// MODE 2: N=1024: out0 f32 = v                                 (final out)
template<int MODE>
__global__ __launch_bounds__(256, 2)
void gemm_bt(const ushort* __restrict__ A, const ushort* __restrict__ Bm, const int K,
             void* __restrict__ out0, void* __restrict__ out1, const float* __restrict__ bias)
{
  __shared__ __align__(16) ushort As[128*32];
  __shared__ __align__(16) ushort Bs[128*32];
  const int tid = threadIdx.x;
  const int wave = tid >> 6, lane = tid & 63;
  const int bm = blockIdx.y, bn = blockIdx.x;
  const int wm = wave >> 1, wn = wave & 1;
  const int lm = lane & 15, kk = (lane >> 4) * 8;
  f32x4 acc[4][4];
  #pragma unroll
  for (int i=0;i<4;i++)
    #pragma unroll
    for (int j=0;j<4;j++) acc[i][j] = (f32x4){0.f,0.f,0.f,0.f};

  const size_t Abase = (size_t)bm*128*K;
  const size_t Bbase = (size_t)bn*128*K;
  for (int k0 = 0; k0 < K; k0 += 32) {
    __syncthreads();
    #pragma unroll
    for (int j=0;j<2;j++){
      int f = j*2048 + tid*8;       // flat bf16 elem within the 128x32 tile
      gld_lds16(A  + Abase + (size_t)(f>>5)*K + k0 + (f&31), &As[j*2048 + wave*512]);
      gld_lds16(Bm + Bbase + (size_t)(f>>5)*K + k0 + (f&31), &Bs[j*2048 + wave*512]);
    }
    __syncthreads();
    bf16x8 af[4], bfv[4];
    #pragma unroll
    for (int mi=0;mi<4;mi++) af[mi]  = *(const bf16x8*)&As[(wm*64+mi*16+lm)*32 + kk];
    #pragma unroll
    for (int ni=0;ni<4;ni++) bfv[ni] = *(const bf16x8*)&Bs[(wn*64+ni*16+lm)*32 + kk];
    #pragma unroll
    for (int mi=0;mi<4;mi++)
      #pragma unroll
      for (int ni=0;ni<4;ni++)
        acc[mi][ni] = __builtin_amdgcn_mfma_f32_16x16x32_bf16(af[mi], bfv[ni], acc[mi][ni], 0, 0, 0);
  }
  const int row0 = bm*128 + wm*64;
  const int col0 = bn*128 + wn*64;
  #pragma unroll
  for (int mi=0;mi<4;mi++){
    #pragma unroll
    for (int ni=0;ni<4;ni++){
      int c = col0 + ni*16 + lm;
      int rbase = row0 + mi*16 + (lane>>4)*4;
      #pragma unroll
      for (int j=0;j<4;j++){
        float v = acc[mi][ni][j];
        size_t rr = (size_t)(rbase + j);
        if (MODE==0){
          if (c < 2048) ((ushort*)out0)[rr*2048 + c] = f2bf(v);
          else          ((ushort*)out1)[rr*2048 + (c-2048)] = f2bf(fsilu(v));
        } else if (MODE==1){
          float u = v + bias[c];
          float sp = (u > 15.f) ? u : logf(1.f + __expf(u));
          ((ushort*)out0)[rr*2048 + c] = f2bf(sp);
        } else if (MODE==2){
          ((float*)out0)[rr*1024 + c] = v;
        }
      }
    }
  }
}

// ---------------- split-K skinny GEMM for Bs: 16384x16x2048, partials over K ----------------
// grid (KSPLIT, LSEQ/128); block 256 = 4 waves; each wave owns 32 rows (2 M-frags).
__global__ __launch_bounds__(256, 2)
void gemm_bs(const ushort* __restrict__ A, const ushort* __restrict__ WxT,
             float* __restrict__ partial)
{
  __shared__ __align__(16) ushort As[128*32];
  __shared__ __align__(16) ushort Bs[16*32];
  const int tid = threadIdx.x;
  const int wave = tid >> 6, lane = tid & 63;
  const int kc = blockIdx.x, bm = blockIdx.y;
  const int lm = lane & 15, kk = (lane >> 4) * 8;
  const int KC = DI / KSPLIT;    // 256
  f32x4 acc[2];
  acc[0] = (f32x4){0.f,0.f,0.f,0.f};
  acc[1] = (f32x4){0.f,0.f,0.f,0.f};
  const size_t Abase = (size_t)bm*128*DI;
  for (int k0 = kc*KC; k0 < (kc+1)*KC; k0 += 32) {
    __syncthreads();
    #pragma unroll
    for (int j=0;j<2;j++){
      int f = j*2048 + tid*8;
      gld_lds16(A + Abase + (size_t)(f>>5)*DI + k0 + (f&31), &As[j*2048 + wave*512]);
    }
    if (wave == 0){
      int f = lane*8;            // 16 rows x 32 cols
      gld_lds16(WxT + (size_t)(f>>5)*DI + k0 + (f&31), &Bs[0]);
    }
    __syncthreads();
    bf16x8 bfv = *(const bf16x8*)&Bs[lm*32 + kk];
    #pragma unroll
    for (int mi=0;mi<2;mi++){
      bf16x8 af = *(const bf16x8*)&As[(wave*32+mi*16+lm)*32 + kk];
      acc[mi] = __builtin_amdgcn_mfma_f32_16x16x32_bf16(af, bfv, acc[mi], 0, 0, 0);
    }
  }
  float* outp = partial + (size_t)kc*LSEQ*DST;
  #pragma unroll
  for (int mi=0;mi<2;mi++){
    int rbase = bm*128 + wave*32 + mi*16 + (lane>>4)*4;
    #pragma unroll
    for (int j=0;j<4;j++)
      outp[(size_t)(rbase+j)*DST + lm] = acc[mi][j];
  }
}

// sum the KSPLIT partials -> BsB
__global__ void reduce_bs(const float* __restrict__ partial, float* __restrict__ out, int n4){
  int i = blockIdx.x*blockDim.x + threadIdx.x;
  if (i >= n4) return;
  float4 s = ((const float4*)partial)[i];
  #pragma unroll
  for (int k=1;k<KSPLIT;k++){
    float4 v = ((const float4*)(partial + (size_t)k*LSEQ*DST))[i];
    s.x += v.x; s.y += v.y; s.z += v.z; s.w += v.w;
  }
  ((float4*)out)[i] = s;
}

// ---------------- depthwise causal conv K=4 + silu, bf16 in/out (one batch) ----------------
__global__ __launch_bounds__(256)
void conv_silu(const ushort* __restrict__ xs_raw, const float* __restrict__ w,
               const float* __restrict__ cb, ushort* __restrict__ out)
{
  int idx = blockIdx.x*256 + threadIdx.x;   // (LSEQ/8)*DI threads
  int c  = idx & (DI-1);
  int l8 = idx >> 11;                       // 0..511
  int l0 = l8*8;
  float w0=w[c*4+0], w1=w[c*4+1], w2=w[c*4+2], w3=w[c*4+3];
  float bias = cb[c];
  const ushort* base = xs_raw + c;
  float v[11];
  #pragma unroll
  for (int i=0;i<11;i++){
    int t = l0 - 3 + i;
    v[i] = (t >= 0) ? bf2f(base[(size_t)t*DI]) : 0.f;
  }
  ushort* ob = out + (size_t)l0*DI + c;
  #pragma unroll
  for (int i=0;i<8;i++){
    float acc = bias + v[i]*w0 + v[i+1]*w1 + v[i+2]*w2 + v[i+3]*w3;
    ob[(size_t)i*DI] = f2bf(fsilu(acc));
  }
}

// decay helpers: fast path builds g^(s+1) from one exp (valid when a2[s]=(s+1)*a2[0])
__device__ __forceinline__ void build_pw(float g, float* pw){
  pw[0]=g;        pw[1]=g*g;       pw[2]=pw[1]*g;    pw[3]=pw[1]*pw[1];
  pw[4]=pw[3]*g;  pw[5]=pw[3]*pw[1]; pw[6]=pw[3]*pw[2]; pw[7]=pw[3]*pw[3];
  pw[8]=pw[7]*g;  pw[9]=pw[7]*pw[1]; pw[10]=pw[7]*pw[2]; pw[11]=pw[7]*pw[3];
  pw[12]=pw[7]*pw[4]; pw[13]=pw[7]*pw[5]; pw[14]=pw[7]*pw[6]; pw[15]=pw[7]*pw[7];
}

// ---------------- scan phase 1: per-chunk local scan, h0=0 (one batch) ----------------
__global__ __launch_bounds__(256)
void scan_phase1(const ushort* __restrict__ dtb, const float* __restrict__ bsb,
                 const float* __restrict__ A2n, float* __restrict__ hlocal,
                 float* __restrict__ sumdt, const int* __restrict__ flagp)
{
  __shared__ __align__(16) float bs_s[CLEN][DST];
  const int c  = blockIdx.x*256 + threadIdx.x;
  const int ch = blockIdx.y;
  ((float4*)bs_s)[threadIdx.x] = ((const float4*)(bsb + (size_t)ch*CLEN*DST))[threadIdx.x];
  __syncthreads();
  float a2[DST];
  #pragma unroll
  for (int i=0;i<4;i++) *(float4*)&a2[i*4] = *(const float4*)&A2n[(size_t)c*DST + i*4];
  float h[DST];
  #pragma unroll
  for (int s=0;s<DST;s++) h[s] = 0.f;
  float sdt = 0.f;
  const ushort* dtp = dtb + (size_t)ch*CLEN*DI + c;
  if (flagp[0] == 0){
    const float a0 = a2[0];
    for (int t=0;t<CLEN;t++){
      float d = bf2f(dtp[(size_t)t*DI]);
      sdt += d;
      float pw[DST];
      build_pw(fexp2(a0*d), pw);
      #pragma unroll
      for (int s=0;s<DST;s++) h[s] = fmaf(h[s], pw[s], bs_s[t][s]);
    }
  } else {
    for (int t=0;t<CLEN;t++){
      float d = bf2f(dtp[(size_t)t*DI]);
      sdt += d;
      #pragma unroll
      for (int s=0;s<DST;s++) h[s] = fmaf(h[s], fexp2(a2[s]*d), bs_s[t][s]);
    }
  }
  size_t o = ((size_t)ch*DI + c)*DST;
  #pragma unroll
  for (int i=0;i<4;i++) *(float4*)&hlocal[o + i*4] = *(float4*)&h[i*4];
  sumdt[(size_t)ch*DI + c] = sdt;
}

// ---------------- scan phase 2: chunk-level prefix over 64 chunks (one batch) ----------------
__global__ void scan_phase2(const float* __restrict__ hlocal, const float* __restrict__ sumdt,
                            const float* __restrict__ A2n, float* __restrict__ hstart)
{
  int id = blockIdx.x*blockDim.x + threadIdx.x;   // DI*DST = 32768
  int s = id & (DST-1);
  int c = id >> 4;
  float a2 = A2n[(size_t)c*DST + s];
  float h = 0.f;
  for (int ch=0; ch<NCHUNK; ++ch){
    size_t o = ((size_t)ch*DI + c)*DST + s;
    hstart[o] = h;
    float sd = sumdt[(size_t)ch*DI + c];
    h = fmaf(h, fexp2(a2*sd), hlocal[o]);
  }
}

// ---------------- scan phase 3: replay with carry, emit y*silu(z) bf16 (one batch) ----------------
__global__ __launch_bounds__(256)
void scan_phase3(const ushort* __restrict__ dtb, const float* __restrict__ bsb,
                 const float* __restrict__ A2n, const float* __restrict__ hstart,
                 const ushort* __restrict__ xsbf, const ushort* __restrict__ szb,
                 const float* __restrict__ Dv, ushort* __restrict__ ybf,
                 const int* __restrict__ flagp)
{
  __shared__ __align__(16) float bs_s[CLEN][DST];
  const int c  = blockIdx.x*256 + threadIdx.x;
  const int ch = blockIdx.y;
  ((float4*)bs_s)[threadIdx.x] = ((const float4*)(bsb + (size_t)ch*CLEN*DST))[threadIdx.x];
  __syncthreads();
  float a2[DST];
  #pragma unroll
  for (int i=0;i<4;i++) *(float4*)&a2[i*4] = *(const float4*)&A2n[(size_t)c*DST + i*4];
  float h[DST];
  size_t ho = ((size_t)ch*DI + c)*DST;
  #pragma unroll
  for (int i=0;i<4;i++) *(float4*)&h[i*4] = *(const float4*)&hstart[ho + i*4];
  const float Dc = Dv[c];
  const size_t base = (size_t)ch*CLEN*DI + c;
  const ushort* dtp = dtb + base;
  const ushort* xp  = xsbf + base;
  const ushort* szp = szb + base;
  ushort* yp = ybf + base;
  const int fast = (flagp[0] == 0);
  const float a0 = a2[0];
  for (int t=0;t<CLEN;t++){
    float d = bf2f(dtp[(size_t)t*DI]);
    if (fast){
      float pw[DST];
      build_pw(fexp2(a0*d), pw);
      #pragma unroll
      for (int s=0;s<DST;s++) h[s] = fmaf(h[s], pw[s], bs_s[t][s]);
    } else {
      #pragma unroll
      for (int s=0;s<DST;s++) h[s] = fmaf(h[s], fexp2(a2[s]*d), bs_s[t][s]);
    }
    float s0 = (h[0]+h[1]) + (h[2]+h[3]);
    float s1 = (h[4]+h[5]) + (h[6]+h[7]);
    float s2 = (h[8]+h[9]) + (h[10]+h[11]);
    float s3 = (h[12]+h[13]) + (h[14]+h[15]);
    float ysum = (s0+s1) + (s2+s3);
    float xv = bf2f(xp[(size_t)t*DI]);
    float yv = fmaf(Dc, xv, ysum);
    yp[(size_t)t*DI] = f2bf(yv * bf2f(szp[(size_t)t*DI]));
  }
}

// ---------------- launch ----------------
extern "C" void kernel_launch(void* const* d_in, const int* in_sizes, int n_in,
                              void* d_out, int out_size, void* d_ws, size_t ws_size,
                              hipStream_t stream)
{
  if (n_in < 10) return;
  const float* x     = (const float*)d_in[0];
  const float* W_in  = (const float*)d_in[1];
  const float* convw = (const float*)d_in[2];
  const float* convb = (const float*)d_in[3];
  const float* A_log = (const float*)d_in[4];
  const float* Dvec  = (const float*)d_in[5];
  const float* W_x   = (const float*)d_in[6];
  const float* W_dt  = (const float*)d_in[7];
  const float* b_dt  = (const float*)d_in[8];
  const float* W_out = (const float*)d_in[9];
  float* out = (float*)d_out;

  char* p = (char*)d_ws;
  auto alloc = [&](size_t n){ char* r = p; p += (n + 255) & ~(size_t)255; return r; };
  // weights (once)
  ushort* WinT   = (ushort*)alloc((size_t)(2*DI)*DMODEL*2);   //  8.4 MB
  ushort* WdtT   = (ushort*)alloc((size_t)DI*DI*2);           //  8.4 MB
  ushort* WoutT  = (ushort*)alloc((size_t)DMODEL*DI*2);       //  4.2 MB
  ushort* WxT    = (ushort*)alloc((size_t)DST*DI*2);          //  64 KB
  float*  A2n    = (float*)alloc((size_t)DI*DST*4);           //  0.1 MB
  int*    flag   = (int*)alloc(256);
  // per-batch activations (reused across the 4 batches)
  ushort* xbf    = (ushort*)alloc((size_t)LSEQ*DMODEL*2);     //  8.4 MB
  ushort* xsr    = (ushort*)alloc((size_t)LSEQ*DI*2);         // 16.8 MB raw xs
  ushort* szb    = (ushort*)alloc((size_t)LSEQ*DI*2);         // 16.8 MB silu(z)
  ushort* xsb    = (ushort*)alloc((size_t)LSEQ*DI*2);         // 16.8 MB conv+silu
  ushort* dtb    = (ushort*)alloc((size_t)LSEQ*DI*2);         // 16.8 MB dt
  ushort* ybf    = (ushort*)alloc((size_t)LSEQ*DI*2);         // 16.8 MB y
  float*  BsB    = (float*)alloc((size_t)LSEQ*DST*4);         //  0.3 MB
  float*  hlocal = (float*)alloc((size_t)NCHUNK*DI*DST*4);    //  8.4 MB
  float*  hstart = (float*)alloc((size_t)NCHUNK*DI*DST*4);    //  8.4 MB (aliased by BsP pre-scan)
  float*  sumdt  = (float*)alloc((size_t)NCHUNK*DI*4);        //  0.5 MB
  if ((size_t)(p - (char*)d_ws) > ws_size) return;   // ws too small: no OOB
  float* BsP = hstart;   // KSPLIT*LSEQ*DST*4 = 4.2 MB fits in hstart's 8.4 MB;
                         // consumed by reduce_bs before scan_phase2 writes hstart.

  // weight prep
  transpose_cast<<<dim3((2*DI)/32, DMODEL/32), dim3(32,8), 0, stream>>>(W_in, WinT, DMODEL, 2*DI);
  transpose_cast<<<dim3(DI/32, DI/32), dim3(32,8), 0, stream>>>(W_dt, WdtT, DI, DI);
  transpose_cast<<<dim3(DMODEL/32, DI/32), dim3(32,8), 0, stream>>>(W_out, WoutT, DI, DMODEL);
  transpose_cast<<<dim3(1, DI/32), dim3(32,8), 0, stream>>>(W_x, WxT, DI, DST);
  prep_a2<<<(DI*DST + 255)/256, 256, 0, stream>>>(A_log, A2n, DI*DST);
  hipMemsetAsync(flag, 0, 4, stream);
  check_a2<<<DI/256, 256, 0, stream>>>(A2n, flag);

  for (int b = 0; b < NBATCH; ++b) {
    const float* xb = x + (size_t)b*LSEQ*DMODEL;
    float* outb = out + (size_t)b*LSEQ*DMODEL;
    // cast x -> bf16
    cast_f32_bf16<<<(LSEQ*DMODEL/4 + 255)/256, 256, 0, stream>>>(xb, xbf, LSEQ*DMODEL/4);
    // xz = x @ W_in ; xs raw bf16 + silu(z) bf16
    gemm_bt<0><<<dim3((2*DI)/128, LSEQ/128), 256, 0, stream>>>(xbf, WinT, DMODEL, xsr, szb, nullptr);
    // depthwise conv + silu -> bf16
    conv_silu<<<(LSEQ/8)*DI/256, 256, 0, stream>>>(xsr, convw, convb, xsb);
    // dt = softplus(xs @ W_dt + b_dt) -> bf16
    gemm_bt<1><<<dim3(DI/128, LSEQ/128), 256, 0, stream>>>(xsb, WdtT, DI, dtb, nullptr, b_dt);
    // Bs = xs @ W_x via split-K partials + reduce -> f32
    gemm_bs<<<dim3(KSPLIT, LSEQ/128), 256, 0, stream>>>(xsb, WxT, BsP);
    reduce_bs<<<(LSEQ*DST/4 + 255)/256, 256, 0, stream>>>(BsP, BsB, LSEQ*DST/4);
    // chunked scan
    scan_phase1<<<dim3(DI/256, NCHUNK), 256, 0, stream>>>(dtb, BsB, A2n, hlocal, sumdt, flag);
    scan_phase2<<<(DI*DST)/256, 256, 0, stream>>>(hlocal, sumdt, A2n, hstart);
    scan_phase3<<<dim3(DI/256, NCHUNK), 256, 0, stream>>>(dtb, BsB, A2n, hstart, xsb, szb, Dvec, ybf, flag);
    // out = y @ W_out (f32)
    gemm_bt<2><<<dim3(DMODEL/128, LSEQ/128), 256, 0, stream>>>(ybf, WoutT, DI, outb, nullptr, nullptr);
  }
}

// Round 4
// 844.964 us; speedup vs baseline: 1.2776x; 1.1370x over previous
//
#include <hip/hip_runtime.h>

typedef __attribute__((ext_vector_type(8))) short bf16x8;
typedef __attribute__((ext_vector_type(4))) float f32x4;

#define NBATCH 4
#define LSEQ   4096
#define DMODEL 1024
#define DI     2048
#define DST    16
#define NCHUNK 64
#define CLEN   (LSEQ/NCHUNK)   // 64
#define KSPLIT 8               // split-K factor for Bs GEMM

// ---------------- helpers ----------------
__device__ __forceinline__ ushort f2bf(float x){
  union { float f; unsigned u; } v; v.f = x;
  unsigned r = v.u + 0x7FFFu + ((v.u >> 16) & 1u);
  return (ushort)(r >> 16);
}
__device__ __forceinline__ float bf2f(ushort h){
  union { unsigned u; float f; } v; v.u = ((unsigned)h) << 16;
  return v.f;
}
__device__ __forceinline__ float fexp2(float x){
  float r; asm("v_exp_f32 %0, %1" : "=v"(r) : "v"(x)); return r;
}
__device__ __forceinline__ float fsilu(float x){
  return x * __builtin_amdgcn_rcpf(1.f + __expf(-x));
}
__device__ __forceinline__ void gld_lds16(const ushort* g, ushort* l){
  __builtin_amdgcn_global_load_lds(
    (const __attribute__((address_space(1))) unsigned int*)g,
    (__attribute__((address_space(3))) unsigned int*)l, 16, 0, 0);
}

// ---------------- elementwise cast f32 -> bf16 (x4 vectorized) ----------------
__global__ void cast_f32_bf16(const float* __restrict__ in, ushort* __restrict__ out, int n4){
  int i = blockIdx.x*blockDim.x + threadIdx.x;
  if (i >= n4) return;
  float4 v = ((const float4*)in)[i];
  ushort4 o; o.x=f2bf(v.x); o.y=f2bf(v.y); o.z=f2bf(v.z); o.w=f2bf(v.w);
  ((ushort4*)out)[i] = o;
}

// ---------------- transpose + cast: out[c][r] = bf16(in[r][c]) ----------------
__global__ void transpose_cast(const float* __restrict__ in, ushort* __restrict__ out, int R, int C){
  __shared__ float tile[32][33];
  int c0 = blockIdx.x*32, r0 = blockIdx.y*32;
  int tx = threadIdx.x, ty = threadIdx.y;   // 32 x 8
  #pragma unroll
  for (int i=0;i<4;i++){
    int r = r0 + ty + i*8;
    if (r < R && (c0+tx) < C) tile[ty+i*8][tx] = in[(size_t)r*C + c0 + tx];
  }
  __syncthreads();
  #pragma unroll
  for (int i=0;i<4;i++){
    int c = c0 + ty + i*8;
    if (c < C && (r0+tx) < R) out[(size_t)c*R + r0 + tx] = f2bf(tile[tx][ty+i*8]);
  }
}

// A2n = -exp(A_log) * log2(e)
__global__ void prep_a2(const float* __restrict__ A_log, float* __restrict__ A2n, int n){
  int i = blockIdx.x*blockDim.x + threadIdx.x;
  if (i < n) A2n[i] = -expf(A_log[i]) * 1.4426950408889634f;
}

// Check whether a2[c][s] == (s+1)*a2[c][0] for all channels (enables 1-exp scan path).
__global__ void check_a2(const float* __restrict__ A2n, int* __restrict__ flag){
  int c = blockIdx.x*blockDim.x + threadIdx.x;
  if (c >= DI) return;
  const float* a = A2n + (size_t)c*DST;
  float a0 = a[0];
  int bad = 0;
  #pragma unroll
  for (int s=1;s<DST;s++){
    float want = (float)(s+1)*a0;
    if (fabsf(a[s] - want) > 1e-4f*fabsf(want) + 1e-12f) bad = 1;
  }
  if (bad) atomicOr(flag, 1);
}

// ======== deep-pipelined bf16 MFMA GEMM (T2+T3+T4+T5), B in N x K layout ========
// 512 threads = 8 waves (WM x WN), BK=32, 4 LDS buffers, stage(t+3) lookahead,
// counted vmcnt at tile boundaries (never 0 in main loop), one barrier per tile.
// LDS swizzle: 16B-slot column c16 ^= (row>>1)&3, applied on BOTH the global
// source address (stage) and the ds_read address; LDS write stays linear
// (global_load_lds requirement).
// MODE 0: N=4096: col<2048 -> out0 bf16 raw (xs), col>=2048 -> out1 bf16 silu (sz)
// MODE 1: N=2048: out0 bf16 = softplus(v + bias[col])         (dt)
// MODE 2: N=1024: out0 f32 = v                                 (final out)
template<int BM, int BN, int WM, int WN, int MODE>
__global__ __launch_bounds__(512, 2)
void gemm8(const ushort* __restrict__ A, const ushort* __restrict__ Bm, const int K,
           void* __restrict__ out0, void* __restrict__ out1, const float* __restrict__ bias)
{
  constexpr int TM = BM/WM, TN = BN/WN;          // per-wave output tile
  constexpr int MR = TM/16, NR = TN/16;          // fragment repeats
  constexpr int AI = BM/128, BI = BN/128;        // gld_lds instrs per wave per tile
  constexpr int L  = AI + BI;                    // loads per wave per tile
  constexpr int SA   = BM*32;                    // A-tile ushorts
  constexpr int SBUF = (BM+BN)*32;               // per-buffer ushorts
  __shared__ __align__(16) ushort lds[4*SBUF];

  const int tid = threadIdx.x;
  const int w = tid >> 6, lane = tid & 63;
  const int lm = lane & 15, lq = lane >> 4;      // frag row / k-quad
  const int wm = w / WN, wn = w % WN;
  const int bn = blockIdx.x, bm = blockIdx.y;
  const int nt = K >> 5;

  const size_t Abase = (size_t)bm*BM*K;
  const size_t Bbase = (size_t)bn*BN*K;

  f32x4 acc[MR][NR];
  #pragma unroll
  for (int i=0;i<MR;i++)
    #pragma unroll
    for (int j=0;j<NR;j++) acc[i][j] = (f32x4){0.f,0.f,0.f,0.f};

  // ---- staging: linear LDS dest, pre-swizzled global source ----
  auto stage = [&](int t){
    ushort* buf = &lds[(size_t)(t & 3)*SBUF];
    const int k0 = t*32;
    #pragma unroll
    for (int i=0;i<AI;i++){
      int slot = (w*AI+i)*64 + lane;             // 16B slot in A-tile
      int row  = slot >> 2;
      int s16  = (lane&3) ^ ((row>>1)&3);        // swizzled source chunk
      gld_lds16(A + Abase + (size_t)row*K + k0 + s16*8, buf + (w*AI+i)*512);
    }
    #pragma unroll
    for (int i=0;i<BI;i++){
      int slot = (w*BI+i)*64 + lane;
      int row  = slot >> 2;
      int s16  = (lane&3) ^ ((row>>1)&3);
      gld_lds16(Bm + Bbase + (size_t)row*K + k0 + s16*8, buf + SA + (w*BI+i)*512);
    }
  };

  // prologue: 3 tiles in flight, wait for tile 0 (leave 2L outstanding)
  stage(0); stage(1); stage(2);
  __builtin_amdgcn_s_waitcnt(0xF70 | (2*L));
  __builtin_amdgcn_sched_barrier(0);
  __builtin_amdgcn_s_barrier();

  for (int t=0; t<nt; ++t){
    if (t+3 < nt) stage(t+3);                    // targets buf[(t-1)&3]: quiesced

    const ushort* bufc = &lds[(size_t)(t & 3)*SBUF];
    bf16x8 af[MR], bfv[NR];
    #pragma unroll
    for (int ni=0;ni<NR;ni++){
      int row = wn*TN + ni*16 + lm;
      bfv[ni] = *(const bf16x8*)&bufc[SA + row*32 + ((lq ^ ((row>>1)&3))<<3)];
    }
    #pragma unroll
    for (int mi=0;mi<MR;mi++){
      int row = wm*TM + mi*16 + lm;
      af[mi] = *(const bf16x8*)&bufc[row*32 + ((lq ^ ((row>>1)&3))<<3)];
    }
    __builtin_amdgcn_s_setprio(1);
    #pragma unroll
    for (int mi=0;mi<MR;mi++)
      #pragma unroll
      for (int ni=0;ni<NR;ni++)
        acc[mi][ni] = __builtin_amdgcn_mfma_f32_16x16x32_bf16(af[mi], bfv[ni], acc[mi][ni], 0, 0, 0);
    __builtin_amdgcn_s_setprio(0);

    if (t+1 < nt){
      if (t+3 < nt)      __builtin_amdgcn_s_waitcnt(0xF70 | (2*L));
      else if (t+2 < nt) __builtin_amdgcn_s_waitcnt(0xF70 | L);
      else               __builtin_amdgcn_s_waitcnt(0xF70);
      __builtin_amdgcn_sched_barrier(0);
      __builtin_amdgcn_s_barrier();
    }
  }

  const int row0 = bm*BM + wm*TM;
  const int col0 = bn*BN + wn*TN;
  #pragma unroll
  for (int mi=0;mi<MR;mi++){
    #pragma unroll
    for (int ni=0;ni<NR;ni++){
      int c = col0 + ni*16 + lm;
      int rbase = row0 + mi*16 + lq*4;
      #pragma unroll
      for (int j=0;j<4;j++){
        float v = acc[mi][ni][j];
        size_t rr = (size_t)(rbase + j);
        if (MODE==0){
          if (c < 2048) ((ushort*)out0)[rr*2048 + c] = f2bf(v);
          else          ((ushort*)out1)[rr*2048 + (c-2048)] = f2bf(fsilu(v));
        } else if (MODE==1){
          float u = v + bias[c];
          float sp = (u > 15.f) ? u : logf(1.f + __expf(u));
          ((ushort*)out0)[rr*2048 + c] = f2bf(sp);
        } else if (MODE==2){
          ((float*)out0)[rr*1024 + c] = v;
        }
      }
    }
  }
}

// ---------------- split-K skinny GEMM for Bs: 4096x16x2048, partials over K ----------------
__global__ __launch_bounds__(256, 2)
void gemm_bs(const ushort* __restrict__ A, const ushort* __restrict__ WxT,
             float* __restrict__ partial)
{
  __shared__ __align__(16) ushort As[128*32];
  __shared__ __align__(16) ushort Bs[16*32];
  const int tid = threadIdx.x;
  const int wave = tid >> 6, lane = tid & 63;
  const int kc = blockIdx.x, bm = blockIdx.y;
  const int lm = lane & 15, kk = (lane >> 4) * 8;
  const int KC = DI / KSPLIT;    // 256
  f32x4 acc[2];
  acc[0] = (f32x4){0.f,0.f,0.f,0.f};
  acc[1] = (f32x4){0.f,0.f,0.f,0.f};
  const size_t Abase = (size_t)bm*128*DI;
  for (int k0 = kc*KC; k0 < (kc+1)*KC; k0 += 32) {
    __syncthreads();
    #pragma unroll
    for (int j=0;j<2;j++){
      int f = j*2048 + tid*8;
      gld_lds16(A + Abase + (size_t)(f>>5)*DI + k0 + (f&31), &As[j*2048 + wave*512]);
    }
    if (wave == 0){
      int f = lane*8;            // 16 rows x 32 cols
      gld_lds16(WxT + (size_t)(f>>5)*DI + k0 + (f&31), &Bs[0]);
    }
    __syncthreads();
    bf16x8 bfv = *(const bf16x8*)&Bs[lm*32 + kk];
    #pragma unroll
    for (int mi=0;mi<2;mi++){
      bf16x8 af = *(const bf16x8*)&As[(wave*32+mi*16+lm)*32 + kk];
      acc[mi] = __builtin_amdgcn_mfma_f32_16x16x32_bf16(af, bfv, acc[mi], 0, 0, 0);
    }
  }
  float* outp = partial + (size_t)kc*LSEQ*DST;
  #pragma unroll
  for (int mi=0;mi<2;mi++){
    int rbase = bm*128 + wave*32 + mi*16 + (lane>>4)*4;
    #pragma unroll
    for (int j=0;j<4;j++)
      outp[(size_t)(rbase+j)*DST + lm] = acc[mi][j];
  }
}

// sum the KSPLIT partials -> BsB
__global__ void reduce_bs(const float* __restrict__ partial, float* __restrict__ out, int n4){
  int i = blockIdx.x*blockDim.x + threadIdx.x;
  if (i >= n4) return;
  float4 s = ((const float4*)partial)[i];
  #pragma unroll
  for (int k=1;k<KSPLIT;k++){
    float4 v = ((const float4*)(partial + (size_t)k*LSEQ*DST))[i];
    s.x += v.x; s.y += v.y; s.z += v.z; s.w += v.w;
  }
  ((float4*)out)[i] = s;
}

// ---------------- depthwise causal conv K=4 + silu, bf16 in/out (one batch) ----------------
__global__ __launch_bounds__(256)
void conv_silu(const ushort* __restrict__ xs_raw, const float* __restrict__ w,
               const float* __restrict__ cb, ushort* __restrict__ out)
{
  int idx = blockIdx.x*256 + threadIdx.x;   // (LSEQ/8)*DI threads
  int c  = idx & (DI-1);
  int l8 = idx >> 11;                       // 0..511
  int l0 = l8*8;
  float w0=w[c*4+0], w1=w[c*4+1], w2=w[c*4+2], w3=w[c*4+3];
  float bias = cb[c];
  const ushort* base = xs_raw + c;
  float v[11];
  #pragma unroll
  for (int i=0;i<11;i++){
    int t = l0 - 3 + i;
    v[i] = (t >= 0) ? bf2f(base[(size_t)t*DI]) : 0.f;
  }
  ushort* ob = out + (size_t)l0*DI + c;
  #pragma unroll
  for (int i=0;i<8;i++){
    float acc = bias + v[i]*w0 + v[i+1]*w1 + v[i+2]*w2 + v[i+3]*w3;
    ob[(size_t)i*DI] = f2bf(fsilu(acc));
  }
}

// decay helpers: fast path builds g^(s+1) from one exp (valid when a2[s]=(s+1)*a2[0])
__device__ __forceinline__ void build_pw(float g, float* pw){
  pw[0]=g;        pw[1]=g*g;       pw[2]=pw[1]*g;    pw[3]=pw[1]*pw[1];
  pw[4]=pw[3]*g;  pw[5]=pw[3]*pw[1]; pw[6]=pw[3]*pw[2]; pw[7]=pw[3]*pw[3];
  pw[8]=pw[7]*g;  pw[9]=pw[7]*pw[1]; pw[10]=pw[7]*pw[2]; pw[11]=pw[7]*pw[3];
  pw[12]=pw[7]*pw[4]; pw[13]=pw[7]*pw[5]; pw[14]=pw[7]*pw[6]; pw[15]=pw[7]*pw[7];
}

// ---------------- scan phase 1: per-chunk local scan, h0=0 (one batch) ----------------
__global__ __launch_bounds__(256)
void scan_phase1(const ushort* __restrict__ dtb, const float* __restrict__ bsb,
                 const float* __restrict__ A2n, float* __restrict__ hlocal,
                 float* __restrict__ sumdt, const int* __restrict__ flagp)
{
  __shared__ __align__(16) float bs_s[CLEN][DST];
  const int c  = blockIdx.x*256 + threadIdx.x;
  const int ch = blockIdx.y;
  ((float4*)bs_s)[threadIdx.x] = ((const float4*)(bsb + (size_t)ch*CLEN*DST))[threadIdx.x];
  __syncthreads();
  float a2[DST];
  #pragma unroll
  for (int i=0;i<4;i++) *(float4*)&a2[i*4] = *(const float4*)&A2n[(size_t)c*DST + i*4];
  float h[DST];
  #pragma unroll
  for (int s=0;s<DST;s++) h[s] = 0.f;
  float sdt = 0.f;
  const ushort* dtp = dtb + (size_t)ch*CLEN*DI + c;
  if (flagp[0] == 0){
    const float a0 = a2[0];
    for (int t=0;t<CLEN;t++){
      float d = bf2f(dtp[(size_t)t*DI]);
      sdt += d;
      float pw[DST];
      build_pw(fexp2(a0*d), pw);
      #pragma unroll
      for (int s=0;s<DST;s++) h[s] = fmaf(h[s], pw[s], bs_s[t][s]);
    }
  } else {
    for (int t=0;t<CLEN;t++){
      float d = bf2f(dtp[(size_t)t*DI]);
      sdt += d;
      #pragma unroll
      for (int s=0;s<DST;s++) h[s] = fmaf(h[s], fexp2(a2[s]*d), bs_s[t][s]);
    }
  }
  size_t o = ((size_t)ch*DI + c)*DST;
  #pragma unroll
  for (int i=0;i<4;i++) *(float4*)&hlocal[o + i*4] = *(float4*)&h[i*4];
  sumdt[(size_t)ch*DI + c] = sdt;
}

// ---------------- scan phase 2: chunk-level prefix over 64 chunks (one batch) ----------------
__global__ void scan_phase2(const float* __restrict__ hlocal, const float* __restrict__ sumdt,
                            const float* __restrict__ A2n, float* __restrict__ hstart)
{
  int id = blockIdx.x*blockDim.x + threadIdx.x;   // DI*DST = 32768
  int s = id & (DST-1);
  int c = id >> 4;
  float a2 = A2n[(size_t)c*DST + s];
  float h = 0.f;
  for (int ch=0; ch<NCHUNK; ++ch){
    size_t o = ((size_t)ch*DI + c)*DST + s;
    hstart[o] = h;
    float sd = sumdt[(size_t)ch*DI + c];
    h = fmaf(h, fexp2(a2*sd), hlocal[o]);
  }
}

// ---------------- scan phase 3: replay with carry, emit y*silu(z) bf16 (one batch) ----------------
__global__ __launch_bounds__(256)
void scan_phase3(const ushort* __restrict__ dtb, const float* __restrict__ bsb,
                 const float* __restrict__ A2n, const float* __restrict__ hstart,
                 const ushort* __restrict__ xsbf, const ushort* __restrict__ szb,
                 const float* __restrict__ Dv, ushort* __restrict__ ybf,
                 const int* __restrict__ flagp)
{
  __shared__ __align__(16) float bs_s[CLEN][DST];
  const int c  = blockIdx.x*256 + threadIdx.x;
  const int ch = blockIdx.y;
  ((float4*)bs_s)[threadIdx.x] = ((const float4*)(bsb + (size_t)ch*CLEN*DST))[threadIdx.x];
  __syncthreads();
  float a2[DST];
  #pragma unroll
  for (int i=0;i<4;i++) *(float4*)&a2[i*4] = *(const float4*)&A2n[(size_t)c*DST + i*4];
  float h[DST];
  size_t ho = ((size_t)ch*DI + c)*DST;
  #pragma unroll
  for (int i=0;i<4;i++) *(float4*)&h[i*4] = *(const float4*)&hstart[ho + i*4];
  const float Dc = Dv[c];
  const size_t base = (size_t)ch*CLEN*DI + c;
  const ushort* dtp = dtb + base;
  const ushort* xp  = xsbf + base;
  const ushort* szp = szb + base;
  ushort* yp = ybf + base;
  const int fast = (flagp[0] == 0);
  const float a0 = a2[0];
  for (int t=0;t<CLEN;t++){
    float d = bf2f(dtp[(size_t)t*DI]);
    if (fast){
      float pw[DST];
      build_pw(fexp2(a0*d), pw);
      #pragma unroll
      for (int s=0;s<DST;s++) h[s] = fmaf(h[s], pw[s], bs_s[t][s]);
    } else {
      #pragma unroll
      for (int s=0;s<DST;s++) h[s] = fmaf(h[s], fexp2(a2[s]*d), bs_s[t][s]);
    }
    float s0 = (h[0]+h[1]) + (h[2]+h[3]);
    float s1 = (h[4]+h[5]) + (h[6]+h[7]);
    float s2 = (h[8]+h[9]) + (h[10]+h[11]);
    float s3 = (h[12]+h[13]) + (h[14]+h[15]);
    float ysum = (s0+s1) + (s2+s3);
    float xv = bf2f(xp[(size_t)t*DI]);
    float yv = fmaf(Dc, xv, ysum);
    yp[(size_t)t*DI] = f2bf(yv * bf2f(szp[(size_t)t*DI]));
  }
}

// ---------------- launch ----------------
extern "C" void kernel_launch(void* const* d_in, const int* in_sizes, int n_in,
                              void* d_out, int out_size, void* d_ws, size_t ws_size,
                              hipStream_t stream)
{
  if (n_in < 10) return;
  const float* x     = (const float*)d_in[0];
  const float* W_in  = (const float*)d_in[1];
  const float* convw = (const float*)d_in[2];
  const float* convb = (const float*)d_in[3];
  const float* A_log = (const float*)d_in[4];
  const float* Dvec  = (const float*)d_in[5];
  const float* W_x   = (const float*)d_in[6];
  const float* W_dt  = (const float*)d_in[7];
  const float* b_dt  = (const float*)d_in[8];
  const float* W_out = (const float*)d_in[9];
  float* out = (float*)d_out;

  char* p = (char*)d_ws;
  auto alloc = [&](size_t n){ char* r = p; p += (n + 255) & ~(size_t)255; return r; };
  // weights (once)
  ushort* WinT   = (ushort*)alloc((size_t)(2*DI)*DMODEL*2);   //  8.4 MB
  ushort* WdtT   = (ushort*)alloc((size_t)DI*DI*2);           //  8.4 MB
  ushort* WoutT  = (ushort*)alloc((size_t)DMODEL*DI*2);       //  4.2 MB
  ushort* WxT    = (ushort*)alloc((size_t)DST*DI*2);          //  64 KB
  float*  A2n    = (float*)alloc((size_t)DI*DST*4);           //  0.1 MB
  int*    flag   = (int*)alloc(256);
  // per-batch activations (reused across the 4 batches)
  ushort* xbf    = (ushort*)alloc((size_t)LSEQ*DMODEL*2);     //  8.4 MB
  ushort* xsr    = (ushort*)alloc((size_t)LSEQ*DI*2);         // 16.8 MB raw xs
  ushort* szb    = (ushort*)alloc((size_t)LSEQ*DI*2);         // 16.8 MB silu(z)
  ushort* xsb    = (ushort*)alloc((size_t)LSEQ*DI*2);         // 16.8 MB conv+silu
  ushort* dtb    = (ushort*)alloc((size_t)LSEQ*DI*2);         // 16.8 MB dt
  ushort* ybf    = (ushort*)alloc((size_t)LSEQ*DI*2);         // 16.8 MB y
  float*  BsB    = (float*)alloc((size_t)LSEQ*DST*4);         //  0.3 MB
  float*  hlocal = (float*)alloc((size_t)NCHUNK*DI*DST*4);    //  8.4 MB
  float*  hstart = (float*)alloc((size_t)NCHUNK*DI*DST*4);    //  8.4 MB (aliased by BsP pre-scan)
  float*  sumdt  = (float*)alloc((size_t)NCHUNK*DI*4);        //  0.5 MB
  if ((size_t)(p - (char*)d_ws) > ws_size) return;   // ws too small: no OOB
  float* BsP = hstart;   // KSPLIT*LSEQ*DST*4 = 4.2 MB fits in hstart's 8.4 MB;
                         // consumed by reduce_bs before scan_phase2 writes hstart.

  // weight prep
  transpose_cast<<<dim3((2*DI)/32, DMODEL/32), dim3(32,8), 0, stream>>>(W_in, WinT, DMODEL, 2*DI);
  transpose_cast<<<dim3(DI/32, DI/32), dim3(32,8), 0, stream>>>(W_dt, WdtT, DI, DI);
  transpose_cast<<<dim3(DMODEL/32, DI/32), dim3(32,8), 0, stream>>>(W_out, WoutT, DI, DMODEL);
  transpose_cast<<<dim3(1, DI/32), dim3(32,8), 0, stream>>>(W_x, WxT, DI, DST);
  prep_a2<<<(DI*DST + 255)/256, 256, 0, stream>>>(A_log, A2n, DI*DST);
  hipMemsetAsync(flag, 0, 4, stream);
  check_a2<<<DI/256, 256, 0, stream>>>(A2n, flag);

  for (int b = 0; b < NBATCH; ++b) {
    const float* xb = x + (size_t)b*LSEQ*DMODEL;
    float* outb = out + (size_t)b*LSEQ*DMODEL;
    // cast x -> bf16
    cast_f32_bf16<<<(LSEQ*DMODEL/4 + 255)/256, 256, 0, stream>>>(xb, xbf, LSEQ*DMODEL/4);
    // xz = x @ W_in ; xs raw bf16 + silu(z) bf16
    gemm8<256,256,2,4,0><<<dim3(4096/256, 4096/256), 512, 0, stream>>>(xbf, WinT, DMODEL, xsr, szb, nullptr);
    // depthwise conv + silu -> bf16
    conv_silu<<<(LSEQ/8)*DI/256, 256, 0, stream>>>(xsr, convw, convb, xsb);
    // dt = softplus(xs @ W_dt + b_dt) -> bf16
    gemm8<128,256,2,4,1><<<dim3(2048/256, 4096/128), 512, 0, stream>>>(xsb, WdtT, DI, dtb, nullptr, b_dt);
    // Bs = xs @ W_x via split-K partials + reduce -> f32
    gemm_bs<<<dim3(KSPLIT, LSEQ/128), 256, 0, stream>>>(xsb, WxT, BsP);
    reduce_bs<<<(LSEQ*DST/4 + 255)/256, 256, 0, stream>>>(BsP, BsB, LSEQ*DST/4);
    // chunked scan
    scan_phase1<<<dim3(DI/256, NCHUNK), 256, 0, stream>>>(dtb, BsB, A2n, hlocal, sumdt, flag);
    scan_phase2<<<(DI*DST)/256, 256, 0, stream>>>(hlocal, sumdt, A2n, hstart);
    scan_phase3<<<dim3(DI/256, NCHUNK), 256, 0, stream>>>(dtb, BsB, A2n, hstart, xsb, szb, Dvec, ybf, flag);
    // out = y @ W_out (f32)
    gemm8<128,128,2,4,2><<<dim3(1024/128, 4096/128), 512, 0, stream>>>(ybf, WoutT, DI, outb, nullptr, nullptr);
  }
}

// Round 5
// 752.197 us; speedup vs baseline: 1.4352x; 1.1233x over previous
//
#include <hip/hip_runtime.h>

typedef __attribute__((ext_vector_type(8))) short bf16x8;
typedef __attribute__((ext_vector_type(4))) float f32x4;

#define NBATCH 4
#define LSEQ   4096
#define DMODEL 1024
#define DI     2048
#define DST    16
#define NCHUNK 128
#define CLEN   (LSEQ/NCHUNK)   // 32
#define KSPLIT 8               // split-K factor for Bs GEMM

// ---------------- helpers ----------------
__device__ __forceinline__ ushort f2bf(float x){
  union { float f; unsigned u; } v; v.f = x;
  unsigned r = v.u + 0x7FFFu + ((v.u >> 16) & 1u);
  return (ushort)(r >> 16);
}
__device__ __forceinline__ float bf2f(ushort h){
  union { unsigned u; float f; } v; v.u = ((unsigned)h) << 16;
  return v.f;
}
__device__ __forceinline__ float fexp2(float x){
  float r; asm("v_exp_f32 %0, %1" : "=v"(r) : "v"(x)); return r;
}
__device__ __forceinline__ float fsilu(float x){
  return x * __builtin_amdgcn_rcpf(1.f + __expf(-x));
}
__device__ __forceinline__ void gld_lds16(const ushort* g, ushort* l){
  __builtin_amdgcn_global_load_lds(
    (const __attribute__((address_space(1))) unsigned int*)g,
    (__attribute__((address_space(3))) unsigned int*)l, 16, 0, 0);
}

// ---------------- elementwise cast f32 -> bf16 (x4 vectorized) ----------------
__global__ void cast_f32_bf16(const float* __restrict__ in, ushort* __restrict__ out, int n4){
  int i = blockIdx.x*blockDim.x + threadIdx.x;
  if (i >= n4) return;
  float4 v = ((const float4*)in)[i];
  ushort4 o; o.x=f2bf(v.x); o.y=f2bf(v.y); o.z=f2bf(v.z); o.w=f2bf(v.w);
  ((ushort4*)out)[i] = o;
}

// ---------------- transpose + cast: out[c][r] = bf16(in[r][c]) ----------------
__global__ void transpose_cast(const float* __restrict__ in, ushort* __restrict__ out, int R, int C){
  __shared__ float tile[32][33];
  int c0 = blockIdx.x*32, r0 = blockIdx.y*32;
  int tx = threadIdx.x, ty = threadIdx.y;   // 32 x 8
  #pragma unroll
  for (int i=0;i<4;i++){
    int r = r0 + ty + i*8;
    if (r < R && (c0+tx) < C) tile[ty+i*8][tx] = in[(size_t)r*C + c0 + tx];
  }
  __syncthreads();
  #pragma unroll
  for (int i=0;i<4;i++){
    int c = c0 + ty + i*8;
    if (c < C && (r0+tx) < R) out[(size_t)c*R + r0 + tx] = f2bf(tile[tx][ty+i*8]);
  }
}

// A2n = -exp(A_log) * log2(e)
__global__ void prep_a2(const float* __restrict__ A_log, float* __restrict__ A2n, int n){
  int i = blockIdx.x*blockDim.x + threadIdx.x;
  if (i < n) A2n[i] = -expf(A_log[i]) * 1.4426950408889634f;
}

// Check whether a2[c][s] == (s+1)*a2[c][0] for all channels (enables 1-exp scan path).
__global__ void check_a2(const float* __restrict__ A2n, int* __restrict__ flag){
  int c = blockIdx.x*blockDim.x + threadIdx.x;
  if (c >= DI) return;
  const float* a = A2n + (size_t)c*DST;
  float a0 = a[0];
  int bad = 0;
  #pragma unroll
  for (int s=1;s<DST;s++){
    float want = (float)(s+1)*a0;
    if (fabsf(a[s] - want) > 1e-4f*fabsf(want) + 1e-12f) bad = 1;
  }
  if (bad) atomicOr(flag, 1);
}

// ======== deep-pipelined bf16 MFMA GEMM (T2+T3+T4+T5), B in N x K layout ========
// 512 threads = 8 waves (WM x WN), BK=32, 4 LDS buffers, stage(t+3) lookahead,
// counted vmcnt at tile boundaries (never 0 in main loop), one barrier per tile.
// LDS swizzle applied on BOTH global source (stage) and ds_read address.
// MODE 0: N=4096: col<2048 -> out0 bf16 raw (xs), col>=2048 -> out1 bf16 silu (sz)
// MODE 1: N=2048: out0 bf16 = softplus(v + bias[col])         (dt)
// MODE 2: N=1024: out0 f32 = v                                 (final out)
template<int BM, int BN, int WM, int WN, int MODE>
__global__ __launch_bounds__(512, 2)
void gemm8(const ushort* __restrict__ A, const ushort* __restrict__ Bm, const int K,
           void* __restrict__ out0, void* __restrict__ out1, const float* __restrict__ bias)
{
  constexpr int TM = BM/WM, TN = BN/WN;          // per-wave output tile
  constexpr int MR = TM/16, NR = TN/16;          // fragment repeats
  constexpr int AI = BM/128, BI = BN/128;        // gld_lds instrs per wave per tile
  constexpr int L  = AI + BI;                    // loads per wave per tile
  constexpr int SA   = BM*32;                    // A-tile ushorts
  constexpr int SBUF = (BM+BN)*32;               // per-buffer ushorts
  __shared__ __align__(16) ushort lds[4*SBUF];

  const int tid = threadIdx.x;
  const int w = tid >> 6, lane = tid & 63;
  const int lm = lane & 15, lq = lane >> 4;      // frag row / k-quad
  const int wm = w / WN, wn = w % WN;
  const int bn = blockIdx.x, bm = blockIdx.y;
  const int nt = K >> 5;

  const size_t Abase = (size_t)bm*BM*K;
  const size_t Bbase = (size_t)bn*BN*K;

  f32x4 acc[MR][NR];
  #pragma unroll
  for (int i=0;i<MR;i++)
    #pragma unroll
    for (int j=0;j<NR;j++) acc[i][j] = (f32x4){0.f,0.f,0.f,0.f};

  // ---- staging: linear LDS dest, pre-swizzled global source ----
  auto stage = [&](int t){
    ushort* buf = &lds[(size_t)(t & 3)*SBUF];
    const int k0 = t*32;
    #pragma unroll
    for (int i=0;i<AI;i++){
      int slot = (w*AI+i)*64 + lane;             // 16B slot in A-tile
      int row  = slot >> 2;
      int s16  = (lane&3) ^ ((row>>1)&3);        // swizzled source chunk
      gld_lds16(A + Abase + (size_t)row*K + k0 + s16*8, buf + (w*AI+i)*512);
    }
    #pragma unroll
    for (int i=0;i<BI;i++){
      int slot = (w*BI+i)*64 + lane;
      int row  = slot >> 2;
      int s16  = (lane&3) ^ ((row>>1)&3);
      gld_lds16(Bm + Bbase + (size_t)row*K + k0 + s16*8, buf + SA + (w*BI+i)*512);
    }
  };

  // prologue: 3 tiles in flight, wait for tile 0 (leave 2L outstanding)
  stage(0); stage(1); stage(2);
  __builtin_amdgcn_s_waitcnt(0xF70 | (2*L));
  __builtin_amdgcn_sched_barrier(0);
  __builtin_amdgcn_s_barrier();

  for (int t=0; t<nt; ++t){
    if (t+3 < nt) stage(t+3);                    // targets buf[(t-1)&3]: quiesced

    const ushort* bufc = &lds[(size_t)(t & 3)*SBUF];
    bf16x8 af[MR], bfv[NR];
    #pragma unroll
    for (int ni=0;ni<NR;ni++){
      int row = wn*TN + ni*16 + lm;
      bfv[ni] = *(const bf16x8*)&bufc[SA + row*32 + ((lq ^ ((row>>1)&3))<<3)];
    }
    #pragma unroll
    for (int mi=0;mi<MR;mi++){
      int row = wm*TM + mi*16 + lm;
      af[mi] = *(const bf16x8*)&bufc[row*32 + ((lq ^ ((row>>1)&3))<<3)];
    }
    __builtin_amdgcn_s_setprio(1);
    #pragma unroll
    for (int mi=0;mi<MR;mi++)
      #pragma unroll
      for (int ni=0;ni<NR;ni++)
        acc[mi][ni] = __builtin_amdgcn_mfma_f32_16x16x32_bf16(af[mi], bfv[ni], acc[mi][ni], 0, 0, 0);
    __builtin_amdgcn_s_setprio(0);

    if (t+1 < nt){
      if (t+3 < nt)      __builtin_amdgcn_s_waitcnt(0xF70 | (2*L));
      else if (t+2 < nt) __builtin_amdgcn_s_waitcnt(0xF70 | L);
      else               __builtin_amdgcn_s_waitcnt(0xF70);
      __builtin_amdgcn_sched_barrier(0);
      __builtin_amdgcn_s_barrier();
    }
  }

  const int row0 = bm*BM + wm*TM;
  const int col0 = bn*BN + wn*TN;
  #pragma unroll
  for (int mi=0;mi<MR;mi++){
    #pragma unroll
    for (int ni=0;ni<NR;ni++){
      int c = col0 + ni*16 + lm;
      int rbase = row0 + mi*16 + lq*4;
      #pragma unroll
      for (int j=0;j<4;j++){
        float v = acc[mi][ni][j];
        size_t rr = (size_t)(rbase + j);
        if (MODE==0){
          if (c < 2048) ((ushort*)out0)[rr*2048 + c] = f2bf(v);
          else          ((ushort*)out1)[rr*2048 + (c-2048)] = f2bf(fsilu(v));
        } else if (MODE==1){
          float u = v + bias[c];
          float sp = (u > 15.f) ? u : logf(1.f + __expf(u));
          ((ushort*)out0)[rr*2048 + c] = f2bf(sp);
        } else if (MODE==2){
          ((float*)out0)[rr*1024 + c] = v;
        }
      }
    }
  }
}

// ---------------- split-K skinny GEMM for Bs: 4096x16x2048, partials over K ----------------
__global__ __launch_bounds__(256, 2)
void gemm_bs(const ushort* __restrict__ A, const ushort* __restrict__ WxT,
             float* __restrict__ partial)
{
  __shared__ __align__(16) ushort As[128*32];
  __shared__ __align__(16) ushort Bs[16*32];
  const int tid = threadIdx.x;
  const int wave = tid >> 6, lane = tid & 63;
  const int kc = blockIdx.x, bm = blockIdx.y;
  const int lm = lane & 15, kk = (lane >> 4) * 8;
  const int KC = DI / KSPLIT;    // 256
  f32x4 acc[2];
  acc[0] = (f32x4){0.f,0.f,0.f,0.f};
  acc[1] = (f32x4){0.f,0.f,0.f,0.f};
  const size_t Abase = (size_t)bm*128*DI;
  for (int k0 = kc*KC; k0 < (kc+1)*KC; k0 += 32) {
    __syncthreads();
    #pragma unroll
    for (int j=0;j<2;j++){
      int f = j*2048 + tid*8;
      gld_lds16(A + Abase + (size_t)(f>>5)*DI + k0 + (f&31), &As[j*2048 + wave*512]);
    }
    if (wave == 0){
      int f = lane*8;            // 16 rows x 32 cols
      gld_lds16(WxT + (size_t)(f>>5)*DI + k0 + (f&31), &Bs[0]);
    }
    __syncthreads();
    bf16x8 bfv = *(const bf16x8*)&Bs[lm*32 + kk];
    #pragma unroll
    for (int mi=0;mi<2;mi++){
      bf16x8 af = *(const bf16x8*)&As[(wave*32+mi*16+lm)*32 + kk];
      acc[mi] = __builtin_amdgcn_mfma_f32_16x16x32_bf16(af, bfv, acc[mi], 0, 0, 0);
    }
  }
  float* outp = partial + (size_t)kc*LSEQ*DST;
  #pragma unroll
  for (int mi=0;mi<2;mi++){
    int rbase = bm*128 + wave*32 + mi*16 + (lane>>4)*4;
    #pragma unroll
    for (int j=0;j<4;j++)
      outp[(size_t)(rbase+j)*DST + lm] = acc[mi][j];
  }
}

// sum the KSPLIT partials -> BsB
__global__ void reduce_bs(const float* __restrict__ partial, float* __restrict__ out, int n4){
  int i = blockIdx.x*blockDim.x + threadIdx.x;
  if (i >= n4) return;
  float4 s = ((const float4*)partial)[i];
  #pragma unroll
  for (int k=1;k<KSPLIT;k++){
    float4 v = ((const float4*)(partial + (size_t)k*LSEQ*DST))[i];
    s.x += v.x; s.y += v.y; s.z += v.z; s.w += v.w;
  }
  ((float4*)out)[i] = s;
}

// ---------------- depthwise causal conv K=4 + silu, bf16 in/out (one batch) ----------------
__global__ __launch_bounds__(256)
void conv_silu(const ushort* __restrict__ xs_raw, const float* __restrict__ w,
               const float* __restrict__ cb, ushort* __restrict__ out)
{
  int idx = blockIdx.x*256 + threadIdx.x;   // (LSEQ/8)*DI threads
  int c  = idx & (DI-1);
  int l8 = idx >> 11;                       // 0..511
  int l0 = l8*8;
  float w0=w[c*4+0], w1=w[c*4+1], w2=w[c*4+2], w3=w[c*4+3];
  float bias = cb[c];
  const ushort* base = xs_raw + c;
  float v[11];
  #pragma unroll
  for (int i=0;i<11;i++){
    int t = l0 - 3 + i;
    v[i] = (t >= 0) ? bf2f(base[(size_t)t*DI]) : 0.f;
  }
  ushort* ob = out + (size_t)l0*DI + c;
  #pragma unroll
  for (int i=0;i<8;i++){
    float acc = bias + v[i]*w0 + v[i+1]*w1 + v[i+2]*w2 + v[i+3]*w3;
    ob[(size_t)i*DI] = f2bf(fsilu(acc));
  }
}

// decay helpers: fast path builds g^(s+1) from one exp (valid when a2[s]=(s+1)*a2[0])
__device__ __forceinline__ void build_pw(float g, float* pw){
  pw[0]=g;        pw[1]=g*g;       pw[2]=pw[1]*g;    pw[3]=pw[1]*pw[1];
  pw[4]=pw[3]*g;  pw[5]=pw[3]*pw[1]; pw[6]=pw[3]*pw[2]; pw[7]=pw[3]*pw[3];
  pw[8]=pw[7]*g;  pw[9]=pw[7]*pw[1]; pw[10]=pw[7]*pw[2]; pw[11]=pw[7]*pw[3];
  pw[12]=pw[7]*pw[4]; pw[13]=pw[7]*pw[5]; pw[14]=pw[7]*pw[6]; pw[15]=pw[7]*pw[7];
}

// ---------------- scan phase 1: per-chunk local scan, h0=0 (one batch) ----------------
__global__ __launch_bounds__(256)
void scan_phase1(const ushort* __restrict__ dtb, const float* __restrict__ bsb,
                 const float* __restrict__ A2n, float* __restrict__ hlocal,
                 float* __restrict__ sumdt, const int* __restrict__ flagp)
{
  __shared__ __align__(16) float bs_s[CLEN][DST];
  const int c  = blockIdx.x*256 + threadIdx.x;
  const int ch = blockIdx.y;
  if (threadIdx.x < CLEN*DST/4)
    ((float4*)bs_s)[threadIdx.x] = ((const float4*)(bsb + (size_t)ch*CLEN*DST))[threadIdx.x];
  __syncthreads();
  float a2[DST];
  #pragma unroll
  for (int i=0;i<4;i++) *(float4*)&a2[i*4] = *(const float4*)&A2n[(size_t)c*DST + i*4];
  float h[DST];
  #pragma unroll
  for (int s=0;s<DST;s++) h[s] = 0.f;
  float sdt = 0.f;
  const ushort* dtp = dtb + (size_t)ch*CLEN*DI + c;
  if (flagp[0] == 0){
    const float a0 = a2[0];
    #pragma unroll 4
    for (int t=0;t<CLEN;t++){
      float d = bf2f(dtp[(size_t)t*DI]);
      sdt += d;
      float pw[DST];
      build_pw(fexp2(a0*d), pw);
      #pragma unroll
      for (int s=0;s<DST;s++) h[s] = fmaf(h[s], pw[s], bs_s[t][s]);
    }
  } else {
    #pragma unroll 2
    for (int t=0;t<CLEN;t++){
      float d = bf2f(dtp[(size_t)t*DI]);
      sdt += d;
      #pragma unroll
      for (int s=0;s<DST;s++) h[s] = fmaf(h[s], fexp2(a2[s]*d), bs_s[t][s]);
    }
  }
  size_t o = ((size_t)ch*DI + c)*DST;
  #pragma unroll
  for (int i=0;i<4;i++) *(float4*)&hlocal[o + i*4] = *(float4*)&h[i*4];
  sumdt[(size_t)ch*DI + c] = sdt;
}

// ---------------- scan phase 2: chunk-level prefix over NCHUNK chunks (one batch) ----------------
__global__ void scan_phase2(const float* __restrict__ hlocal, const float* __restrict__ sumdt,
                            const float* __restrict__ A2n, float* __restrict__ hstart)
{
  int id = blockIdx.x*blockDim.x + threadIdx.x;   // DI*DST = 32768
  int s = id & (DST-1);
  int c = id >> 4;
  float a2 = A2n[(size_t)c*DST + s];
  float h = 0.f;
  for (int ch=0; ch<NCHUNK; ++ch){
    size_t o = ((size_t)ch*DI + c)*DST + s;
    hstart[o] = h;
    float sd = sumdt[(size_t)ch*DI + c];
    h = fmaf(h, fexp2(a2*sd), hlocal[o]);
  }
}

// ---------------- scan phase 3: replay with carry, emit y*silu(z) bf16 (one batch) ----------------
__global__ __launch_bounds__(256)
void scan_phase3(const ushort* __restrict__ dtb, const float* __restrict__ bsb,
                 const float* __restrict__ A2n, const float* __restrict__ hstart,
                 const ushort* __restrict__ xsbf, const ushort* __restrict__ szb,
                 const float* __restrict__ Dv, ushort* __restrict__ ybf,
                 const int* __restrict__ flagp)
{
  __shared__ __align__(16) float bs_s[CLEN][DST];
  const int c  = blockIdx.x*256 + threadIdx.x;
  const int ch = blockIdx.y;
  if (threadIdx.x < CLEN*DST/4)
    ((float4*)bs_s)[threadIdx.x] = ((const float4*)(bsb + (size_t)ch*CLEN*DST))[threadIdx.x];
  __syncthreads();
  float a2[DST];
  #pragma unroll
  for (int i=0;i<4;i++) *(float4*)&a2[i*4] = *(const float4*)&A2n[(size_t)c*DST + i*4];
  float h[DST];
  size_t ho = ((size_t)ch*DI + c)*DST;
  #pragma unroll
  for (int i=0;i<4;i++) *(float4*)&h[i*4] = *(const float4*)&hstart[ho + i*4];
  const float Dc = Dv[c];
  const size_t base = (size_t)ch*CLEN*DI + c;
  const ushort* dtp = dtb + base;
  const ushort* xp  = xsbf + base;
  const ushort* szp = szb + base;
  ushort* yp = ybf + base;
  const int fast = (flagp[0] == 0);
  const float a0 = a2[0];
  if (fast){
    #pragma unroll 4
    for (int t=0;t<CLEN;t++){
      float d = bf2f(dtp[(size_t)t*DI]);
      float pw[DST];
      build_pw(fexp2(a0*d), pw);
      #pragma unroll
      for (int s=0;s<DST;s++) h[s] = fmaf(h[s], pw[s], bs_s[t][s]);
      float s0 = (h[0]+h[1]) + (h[2]+h[3]);
      float s1 = (h[4]+h[5]) + (h[6]+h[7]);
      float s2 = (h[8]+h[9]) + (h[10]+h[11]);
      float s3 = (h[12]+h[13]) + (h[14]+h[15]);
      float ysum = (s0+s1) + (s2+s3);
      float xv = bf2f(xp[(size_t)t*DI]);
      float yv = fmaf(Dc, xv, ysum);
      yp[(size_t)t*DI] = f2bf(yv * bf2f(szp[(size_t)t*DI]));
    }
  } else {
    #pragma unroll 2
    for (int t=0;t<CLEN;t++){
      float d = bf2f(dtp[(size_t)t*DI]);
      #pragma unroll
      for (int s=0;s<DST;s++) h[s] = fmaf(h[s], fexp2(a2[s]*d), bs_s[t][s]);
      float s0 = (h[0]+h[1]) + (h[2]+h[3]);
      float s1 = (h[4]+h[5]) + (h[6]+h[7]);
      float s2 = (h[8]+h[9]) + (h[10]+h[11]);
      float s3 = (h[12]+h[13]) + (h[14]+h[15]);
      float ysum = (s0+s1) + (s2+s3);
      float xv = bf2f(xp[(size_t)t*DI]);
      float yv = fmaf(Dc, xv, ysum);
      yp[(size_t)t*DI] = f2bf(yv * bf2f(szp[(size_t)t*DI]));
    }
  }
}

// ---------------- launch ----------------
extern "C" void kernel_launch(void* const* d_in, const int* in_sizes, int n_in,
                              void* d_out, int out_size, void* d_ws, size_t ws_size,
                              hipStream_t stream)
{
  if (n_in < 10) return;
  const float* x     = (const float*)d_in[0];
  const float* W_in  = (const float*)d_in[1];
  const float* convw = (const float*)d_in[2];
  const float* convb = (const float*)d_in[3];
  const float* A_log = (const float*)d_in[4];
  const float* Dvec  = (const float*)d_in[5];
  const float* W_x   = (const float*)d_in[6];
  const float* W_dt  = (const float*)d_in[7];
  const float* b_dt  = (const float*)d_in[8];
  const float* W_out = (const float*)d_in[9];
  float* out = (float*)d_out;

  char* p = (char*)d_ws;
  auto alloc = [&](size_t n){ char* r = p; p += (n + 255) & ~(size_t)255; return r; };
  // weights (once)
  ushort* WinT   = (ushort*)alloc((size_t)(2*DI)*DMODEL*2);   //  8.4 MB
  ushort* WdtT   = (ushort*)alloc((size_t)DI*DI*2);           //  8.4 MB
  ushort* WoutT  = (ushort*)alloc((size_t)DMODEL*DI*2);       //  4.2 MB
  ushort* WxT    = (ushort*)alloc((size_t)DST*DI*2);          //  64 KB
  float*  A2n    = (float*)alloc((size_t)DI*DST*4);           //  0.1 MB
  int*    flag   = (int*)alloc(256);
  // per-batch activations (reused across the 4 batches)
  ushort* xbf    = (ushort*)alloc((size_t)LSEQ*DMODEL*2);     //  8.4 MB
  ushort* xsr    = (ushort*)alloc((size_t)LSEQ*DI*2);         // 16.8 MB raw xs; dead after conv -> reused as hlocal
  ushort* szb    = (ushort*)alloc((size_t)LSEQ*DI*2);         // 16.8 MB silu(z)
  ushort* xsb    = (ushort*)alloc((size_t)LSEQ*DI*2);         // 16.8 MB conv+silu
  ushort* dtb    = (ushort*)alloc((size_t)LSEQ*DI*2);         // 16.8 MB dt
  ushort* ybf    = (ushort*)alloc((size_t)LSEQ*DI*2);         // 16.8 MB y
  float*  BsB    = (float*)alloc((size_t)LSEQ*DST*4);         //  0.3 MB
  float*  hstart = (float*)alloc((size_t)NCHUNK*DI*DST*4);    // 16.8 MB (aliased by BsP pre-scan)
  float*  sumdt  = (float*)alloc((size_t)NCHUNK*DI*4);        //  1.0 MB
  if ((size_t)(p - (char*)d_ws) > ws_size) return;   // ws too small: no OOB
  float* hlocal = (float*)xsr;   // NCHUNK*DI*DST*4 = 16.8 MB == xsr size; xsr dead after conv,
                                 // hlocal dead after phase2 (before next batch's gemm0 rewrites xsr)
  float* BsP = hstart;           // KSPLIT*LSEQ*DST*4 = 4.2 MB < 16.8 MB; consumed by reduce_bs
                                 // before scan_phase2 writes hstart.

  // weight prep
  transpose_cast<<<dim3((2*DI)/32, DMODEL/32), dim3(32,8), 0, stream>>>(W_in, WinT, DMODEL, 2*DI);
  transpose_cast<<<dim3(DI/32, DI/32), dim3(32,8), 0, stream>>>(W_dt, WdtT, DI, DI);
  transpose_cast<<<dim3(DMODEL/32, DI/32), dim3(32,8), 0, stream>>>(W_out, WoutT, DI, DMODEL);
  transpose_cast<<<dim3(1, DI/32), dim3(32,8), 0, stream>>>(W_x, WxT, DI, DST);
  prep_a2<<<(DI*DST + 255)/256, 256, 0, stream>>>(A_log, A2n, DI*DST);
  hipMemsetAsync(flag, 0, 4, stream);
  check_a2<<<DI/256, 256, 0, stream>>>(A2n, flag);

  for (int b = 0; b < NBATCH; ++b) {
    const float* xb = x + (size_t)b*LSEQ*DMODEL;
    float* outb = out + (size_t)b*LSEQ*DMODEL;
    // cast x -> bf16
    cast_f32_bf16<<<(LSEQ*DMODEL/4 + 255)/256, 256, 0, stream>>>(xb, xbf, LSEQ*DMODEL/4);
    // xz = x @ W_in ; xs raw bf16 + silu(z) bf16
    gemm8<256,256,2,4,0><<<dim3(4096/256, 4096/256), 512, 0, stream>>>(xbf, WinT, DMODEL, xsr, szb, nullptr);
    // depthwise conv + silu -> bf16
    conv_silu<<<(LSEQ/8)*DI/256, 256, 0, stream>>>(xsr, convw, convb, xsb);
    // dt = softplus(xs @ W_dt + b_dt) -> bf16
    gemm8<128,256,2,4,1><<<dim3(2048/256, 4096/128), 512, 0, stream>>>(xsb, WdtT, DI, dtb, nullptr, b_dt);
    // Bs = xs @ W_x via split-K partials + reduce -> f32
    gemm_bs<<<dim3(KSPLIT, LSEQ/128), 256, 0, stream>>>(xsb, WxT, BsP);
    reduce_bs<<<(LSEQ*DST/4 + 255)/256, 256, 0, stream>>>(BsP, BsB, LSEQ*DST/4);
    // chunked scan (hlocal lives in xsr's storage)
    scan_phase1<<<dim3(DI/256, NCHUNK), 256, 0, stream>>>(dtb, BsB, A2n, hlocal, sumdt, flag);
    scan_phase2<<<(DI*DST)/256, 256, 0, stream>>>(hlocal, sumdt, A2n, hstart);
    scan_phase3<<<dim3(DI/256, NCHUNK), 256, 0, stream>>>(dtb, BsB, A2n, hstart, xsb, szb, Dvec, ybf, flag);
    // out = y @ W_out (f32)
    gemm8<128,128,2,4,2><<<dim3(1024/128, 4096/128), 512, 0, stream>>>(ybf, WoutT, DI, outb, nullptr, nullptr);
  }
}